// Round 4
// baseline (385.445 us; speedup 1.0000x reference)
//
#include <hip/hip_runtime.h>
#include <stdint.h>

// QuickDistogram: N=32768, K=64, C=256, PAIR=32, HID=64, BINS=16, CLIP=32.
// Outputs: log_p [N*K*16] then dmap [N*K] (fp32).
// v3: fp16 packed-math pipeline (v2) + 1-iteration-deep software pipeline on
// the gather chain.  v2 showed FETCH 62->351 MB (gather L2 residency lost) and
// became latency-bound (VALU 41%, HBM 43%, dur 155us).  nb is prefetched 2
// iters ahead; meta[nb]/rightbf[nb] issue one full iteration before use, so
// even HBM-miss latency (~900cy) hides under the ~600cy compute of one group.
#define N_RES 32768
#define KNEI  64
#define CFEAT 256
#define PAIRD 32
#define HIDD  64
#define NBINS 16
#define CLIPV 32
#define NGROUPS (N_RES * KNEI / 16)   // 131072 groups of 16 pairs

typedef __attribute__((ext_vector_type(2))) _Float16 half2_t;
typedef __attribute__((ext_vector_type(8))) _Float16 half8_t;
typedef __attribute__((ext_vector_type(2))) __fp16   fp16v2;
typedef __attribute__((ext_vector_type(4))) float    float4_t;

union H2U { uint32_t u; half2_t h; fp16v2 f; };
union V4H { uint4 v; uint32_t u[4]; half2_t h2[4]; };
union V8H { uint32_t u[4]; half2_t h2[4]; half8_t h8; };

// pack two fp32 -> fp16x2 (v_cvt_pkrtz_f16_f32, 1 inst). low16 = a, high16 = b.
__device__ __forceinline__ uint32_t pkh(float a, float b) {
    H2U c; c.f = __builtin_amdgcn_cvt_pkrtz(a, b);
    return c.u;
}
__device__ __forceinline__ half2_t pkh2(float a, float b) {
    H2U c; c.f = __builtin_amdgcn_cvt_pkrtz(a, b);
    return c.h;
}

__device__ __forceinline__ float fastrcp(float x) { return __builtin_amdgcn_rcpf(x); }
__device__ __forceinline__ float fexp2(float x)   { return __builtin_amdgcn_exp2f(x); }
__device__ __forceinline__ float flog2(float x)   { return __builtin_amdgcn_logf(x); }

// packed fp16 add through a uint32 (for cross-lane packed reductions)
__device__ __forceinline__ uint32_t addph(uint32_t a, uint32_t b) {
    H2U x, y; x.u = a; y.u = b; x.h = x.h + y.h; return x.u;
}

// tanh-form GELU on 2 packed fp16 values, division- and trans-free.
// Pade(7,6) tanh, rescaled v=(y/4)^2; |y| clamped to 4.5; 1/Nb via
// integer-magic seed + 2 packed Newton steps (~2e-4 rel).
__device__ __forceinline__ half2_t gelu2(half2_t x) {
    const half2_t kA1  = {(_Float16)0.79788456f, (_Float16)0.79788456f};
    const half2_t kA2  = {(_Float16)0.035677408f,(_Float16)0.035677408f};
    const half2_t kPA1 = {(_Float16)2.0512820f,  (_Float16)2.0512820f};
    const half2_t kPA2 = {(_Float16)0.7160840f,  (_Float16)0.7160840f};
    const half2_t kPA3 = {(_Float16)0.0303104f,  (_Float16)0.0303104f};
    const half2_t kPB1 = {(_Float16)7.3846154f,  (_Float16)7.3846154f};
    const half2_t kPB2 = {(_Float16)5.9673660f,  (_Float16)5.9673660f};
    const half2_t kPB3 = {(_Float16)0.8486920f,  (_Float16)0.8486920f};
    const half2_t kOne = {(_Float16)1.0f,  (_Float16)1.0f};
    const half2_t kTwo = {(_Float16)2.0f,  (_Float16)2.0f};
    const half2_t kQtr = {(_Float16)0.25f, (_Float16)0.25f};
    const half2_t kHlf = {(_Float16)0.5f,  (_Float16)0.5f};
    const half2_t kClp = {(_Float16)4.5f,  (_Float16)4.5f};
    const half2_t kNCl = {(_Float16)-4.5f, (_Float16)-4.5f};

    half2_t u0 = x * x;
    half2_t y  = x * __builtin_elementwise_fma(kA2, u0, kA1);
    y = __builtin_elementwise_min(__builtin_elementwise_max(y, kNCl), kClp);
    half2_t yq = y * kQtr;
    half2_t v  = yq * yq;                      // v = (y/4)^2 <= 1.266
    half2_t pa = __builtin_elementwise_fma(kPA3, v, kPA2);
    pa = __builtin_elementwise_fma(pa, v, kPA1);
    pa = __builtin_elementwise_fma(pa, v, kOne);
    half2_t pb = __builtin_elementwise_fma(kPB3, v, kPB2);
    pb = __builtin_elementwise_fma(pb, v, kPB1);
    pb = __builtin_elementwise_fma(pb, v, kOne); // pb in [1, 21.7]
    half2_t a = y * pa;
    H2U cb, cr;
    cb.h = pb;
    cr.u = 0x78007800u - cb.u;                 // packed reciprocal seed
    half2_t r = cr.h;
    r = r * __builtin_elementwise_fma(-pb, r, kTwo);
    r = r * __builtin_elementwise_fma(-pb, r, kTwo);
    half2_t th = a * r;
    half2_t hx = x * kHlf;
    return __builtin_elementwise_fma(hx, th, hx);
}

// ---------------------------------------------------------------------------
// Kernel 1: left/right = feat @ W_{l,r} (fp32 VALU) -> fp16 tables, packed
// meta dword, fp16 wpos table.  grid=1024: blocks 0..511 do LEFT (and meta),
// 512..1023 do RIGHT.  32KB LDS/block -> 4 blocks/CU.
// ---------------------------------------------------------------------------
__global__ __launch_bounds__(256) void proj_kernel(
    const float* __restrict__ feat, const float* __restrict__ Wl,
    const float* __restrict__ Wr, const int* __restrict__ resi,
    const int* __restrict__ chain, const int* __restrict__ batch,
    const float* __restrict__ wpos,
    uint4* __restrict__ leftbf, uint4* __restrict__ rightbf,
    uint32_t* __restrict__ meta, uint32_t* __restrict__ wposbf)
{
    __shared__ __align__(16) float Wc[CFEAT * 32];   // 32 KB
    const int tid   = threadIdx.x;
    const int half  = blockIdx.x >> 9;               // 0 = left, 1 = right
    const int rb    = (blockIdx.x & 511) * 64;
    const float* W  = half ? Wr : Wl;
    uint4* outtb    = half ? rightbf : leftbf;

    for (int idx = tid; idx < CFEAT * 32; idx += 256)
        Wc[idx] = W[idx];
    if (half == 0 && tid < 64) {
        int r = rb + tid;
        meta[r] = (uint32_t)resi[r] | ((uint32_t)chain[r] << 16)
                | ((uint32_t)batch[r] << 19);
    }
    if (blockIdx.x == 0) {
        for (int i = tid; i < (2 * CLIPV + 1) * PAIRD / 2; i += 256)
            wposbf[i] = pkh(wpos[2 * i], wpos[2 * i + 1]);
    }
    __syncthreads();

    const int cb  = (tid & 3) * 8;        // 8 of 32 output cols
    const int row = rb + (tid >> 2);      // 1 row

    float acc[8];
#pragma unroll
    for (int j = 0; j < 8; ++j) acc[j] = 0.f;

    for (int i = 0; i < CFEAT; i += 4) {
        float4_t f = *(const float4_t*)(feat + (size_t)row * CFEAT + i);
#pragma unroll
        for (int s = 0; s < 4; ++s) {
            float4_t wa = *(const float4_t*)(Wc + (i + s) * 32 + cb);
            float4_t wb = *(const float4_t*)(Wc + (i + s) * 32 + cb + 4);
#pragma unroll
            for (int j = 0; j < 4; ++j) {
                acc[j]     = __builtin_fmaf(f[s], wa[j], acc[j]);
                acc[4 + j] = __builtin_fmaf(f[s], wb[j], acc[4 + j]);
            }
        }
    }
    uint2 o, o2;
    o.x  = pkh(acc[0], acc[1]);
    o.y  = pkh(acc[2], acc[3]);
    o2.x = pkh(acc[4], acc[5]);
    o2.y = pkh(acc[6], acc[7]);
    uint2* dst = (uint2*)outtb + (size_t)row * 8 + (cb >> 2);
    dst[0] = o;
    dst[1] = o2;
}

// ---------------------------------------------------------------------------
// Kernel 2: per-pair dcode -> LN -> MLP(MFMA f16) -> log_softmax -> outputs.
// One wave = 16 pairs; lane (q=lane>>4, c=lane&15) holds dims 8q..8q+7 of
// pair c.  Packed fp16 math + 1-iter software pipeline on the gather chain.
// Every wave runs exactly 16 iterations (131072 groups / 8192 waves).
// ---------------------------------------------------------------------------
__global__ __launch_bounds__(256, 8) void pair_kernel(
    const uint4* __restrict__ leftbf, const uint4* __restrict__ rightbf,
    const uint32_t* __restrict__ meta, const int* __restrict__ nbr,
    const uint32_t* __restrict__ wposbf,
    const float* __restrict__ lnS, const float* __restrict__ lnB,
    const float* __restrict__ W1, const float* __restrict__ b1,
    const float* __restrict__ W2, const float* __restrict__ b2,
    float* __restrict__ out_logp, float* __restrict__ out_dmap)
{
    __shared__ __align__(16) unsigned char Hbuf[4][16 * 144]; // wave-private H transpose
    __shared__ __align__(16) float b1p[HIDD];                 // b1 + lnB @ W1 (fp32)

    const int tid    = threadIdx.x;
    const int lane   = tid & 63;
    const int wlocal = tid >> 6;
    const int q      = lane >> 4;
    const int c      = lane & 15;

    // ---- preamble: fold ln_bias through W1 into b1' ----
    if (tid < HIDD) {
        float s = b1[tid];
        for (int k = 0; k < PAIRD; ++k)
            s = __builtin_fmaf(lnB[k], W1[k * HIDD + tid], s);
        b1p[tid] = s;
    }

    // ---- weight fragments: W1' = diag(ln_scale) @ W1, A-frag of W1'^T (fp16) ----
    half8_t w1a[4];
#pragma unroll
    for (int t = 0; t < 4; ++t) {
        V8H tmp;
#pragma unroll
        for (int v = 0; v < 4; ++v) {
            int k0 = q * 8 + 2 * v, k1 = k0 + 1;
            float a0 = lnS[k0] * W1[k0 * HIDD + 16 * t + c];
            float a1 = lnS[k1] * W1[k1 * HIDD + 16 * t + c];
            tmp.u[v] = pkh(a0, a1);
        }
        w1a[t] = tmp.h8;
    }
    half8_t w2a[2];                        // A-frag of W2^T, K-tile kt (fp16)
#pragma unroll
    for (int kt = 0; kt < 2; ++kt) {
        V8H tmp;
#pragma unroll
        for (int v = 0; v < 4; ++v) {
            int k0 = kt * 32 + q * 8 + 2 * v;
            tmp.u[v] = pkh(W2[k0 * NBINS + c], W2[(k0 + 1) * NBINS + c]);
        }
        w2a[kt] = tmp.h8;
    }
    const float4_t b2f = *(const float4_t*)(b2 + 4 * q);   // C-init for layer 2

    __syncthreads();   // b1p ready

    const int wglobal = (blockIdx.x * 256 + tid) >> 6;
    const int nwaves  = (gridDim.x * 256) >> 6;
    if (wglobal >= NGROUPS) return;

    // ---- pipeline prologue: stage-0 data + nb for stage 1 ----
    int g = wglobal;
    int gn = g + nwaves; if (gn >= NGROUPS) gn = wglobal;

    int      nb0 = __builtin_nontemporal_load(nbr + g * 16 + c);
    uint32_t mn0 = meta[g >> 2];
    uint4    lf0 = leftbf[(size_t)(g >> 2) * 4 + q];
    int      nb1 = __builtin_nontemporal_load(nbr + gn * 16 + c);
    uint32_t mb0 = meta[nb0];
    uint4    rf0 = rightbf[(size_t)nb0 * 4 + q];

    for (; g < NGROUPS; g += nwaves) {
        const int p = g * 16 + c;

        // ---- prefetch for next iteration (issue before current compute) ----
        int g2 = gn + nwaves; if (g2 >= NGROUPS) g2 = wglobal;
        const int      nb2 = __builtin_nontemporal_load(nbr + g2 * 16 + c);
        const uint32_t mn1 = meta[gn >> 2];
        const uint4    lf1 = leftbf[(size_t)(gn >> 2) * 4 + q];
        const uint32_t mb1 = meta[nb1];                       // nb1: 1 iter in flight
        const uint4    rf1 = rightbf[(size_t)nb1 * 4 + q];

        // ---- current iteration: rel/mask from resident mb0/mn0, pw L1 load ----
        const int rel = min(max((int)(mb0 & 0xFFFFu) - (int)(mn0 & 0xFFFFu),
                                -CLIPV), CLIPV) + CLIPV;
        const uint32_t mskbits = (((mb0 ^ mn0) & 0xFFFF0000u) == 0u)
                               ? 0x3C003C00u : 0u;            // half2(1,1) or (0,0)
        const uint4 pw = *(const uint4*)(wposbf + rel * 16 + q * 4);  // 4KB L1-res

        // ---- dcode dims 8q..8q+7 of pair c, packed fp16 ----
        V4H lu, ru, pu; lu.v = lf0; ru.v = rf0; pu.v = pw;
        H2U mm; mm.u = mskbits;
        const half2_t m2 = mm.h;
        half2_t d2[4];
#pragma unroll
        for (int v = 0; v < 4; ++v)
            d2[v] = __builtin_elementwise_fma(pu.h2[v], m2, lu.h2[v] + ru.h2[v]);

        // ---- LayerNorm stats over 32 dims (packed partial sums) ----
        half2_t a1 = (d2[0] + d2[1]) + (d2[2] + d2[3]);
        half2_t aq = __builtin_elementwise_fma(d2[0], d2[0],
                     __builtin_elementwise_fma(d2[1], d2[1],
                     __builtin_elementwise_fma(d2[2], d2[2], d2[3] * d2[3])));
        H2U c1, c2; c1.h = a1; c2.h = aq;
        uint32_t s1p = c1.u, s2p = c2.u;
        s1p = addph(s1p, (uint32_t)__shfl_xor((int)s1p, 16, 64));
        s1p = addph(s1p, (uint32_t)__shfl_xor((int)s1p, 32, 64));
        s2p = addph(s2p, (uint32_t)__shfl_xor((int)s2p, 16, 64));
        s2p = addph(s2p, (uint32_t)__shfl_xor((int)s2p, 32, 64));
        H2U f1, f2; f1.u = s1p; f2.u = s2p;
        const float s1 = (float)f1.h[0] + (float)f1.h[1];
        const float s2 = (float)f2.h[0] + (float)f2.h[1];
        const float mu   = s1 * (1.0f / 32.0f);
        const float var  = __builtin_fmaf(-mu, mu, s2 * (1.0f / 32.0f));
        const float rstd = __builtin_amdgcn_rsqf(var + 1e-5f);
        const float sh   = -mu * rstd;

        const half2_t rs2 = pkh2(rstd, rstd);
        const half2_t sh2 = pkh2(sh, sh);
        V8H dn;
#pragma unroll
        for (int v = 0; v < 4; ++v)
            dn.h2[v] = __builtin_elementwise_fma(d2[v], rs2, sh2);
        const half8_t dfrag = dn.h8;     // B-frag: B[k=q*8+j][n=c]

        // ---- layer 1 (bias b1' as MFMA C operand, broadcast LDS read) ----
        float4_t hacc[4];
#pragma unroll
        for (int t = 0; t < 4; ++t) {
            float4_t c1v = *(const float4_t*)(b1p + 16 * t + 4 * q);
            hacc[t] = __builtin_amdgcn_mfma_f32_16x16x32_f16(w1a[t], dfrag, c1v, 0, 0, 0);
        }

        // ---- GELU (packed fp16) + store to LDS (transpose to layer-2 B-frag) ----
        unsigned char* hb = &Hbuf[wlocal][0] + c * 144;
#pragma unroll
        for (int t = 0; t < 4; ++t) {
            half2_t g01 = gelu2(pkh2(hacc[t][0], hacc[t][1]));
            half2_t g23 = gelu2(pkh2(hacc[t][2], hacc[t][3]));
            union { half2_t h[2]; uint2 u2; } w;
            w.h[0] = g01; w.h[1] = g23;
            *(uint2*)(hb + 32 * t + 8 * q) = w.u2;   // hid 16t+4q+0..3 of pair c
        }
        const half8_t hf0 = *(const half8_t*)(hb + 16 * q);        // hid 8q..8q+7
        const half8_t hf1 = *(const half8_t*)(hb + 64 + 16 * q);   // hid 32+8q..

        // ---- layer 2 (b2 as C operand): lane holds bins 4q..4q+3 of pair c ----
        float4_t lacc;
        lacc = __builtin_amdgcn_mfma_f32_16x16x32_f16(w2a[0], hf0, b2f,  0, 0, 0);
        lacc = __builtin_amdgcn_mfma_f32_16x16x32_f16(w2a[1], hf1, lacc, 0, 0, 0);

        // ---- log-softmax without max-subtraction (logits are O(+-10)) ----
        const float LOG2E = 1.4426950408889634f, LN2 = 0.6931471805599453f;
        float e[4];
#pragma unroll
        for (int r = 0; r < 4; ++r) e[r] = fexp2(lacc[r] * LOG2E);
        float ssum = (e[0] + e[1]) + (e[2] + e[3]);
        ssum += __shfl_xor(ssum, 16, 64);
        ssum += __shfl_xor(ssum, 32, 64);
        const float lse = flog2(ssum) * LN2;

        // ---- NT stores: bypass/no-allocate L2, keep it for the gathers ----
        float4_t lp = {lacc[0] - lse, lacc[1] - lse, lacc[2] - lse, lacc[3] - lse};
        __builtin_nontemporal_store(lp, (float4_t*)(out_logp + (size_t)p * NBINS + 4 * q));

        const float step  = 22.0f / NBINS;
        const float cbase = (4 * q + 0.5f) * step;
        float dpart = e[0] * cbase + e[1] * (cbase + step)
                    + e[2] * (cbase + 2 * step) + e[3] * (cbase + 3 * step);
        dpart += __shfl_xor(dpart, 16, 64);
        dpart += __shfl_xor(dpart, 32, 64);
        if (q == 0)
            __builtin_nontemporal_store(dpart * fastrcp(ssum), out_dmap + p);

        // ---- rotate pipeline registers ----
        nb1 = nb2; mn0 = mn1; mb0 = mb1; lf0 = lf1; rf0 = rf1; gn = g2;
    }
}

// ---------------------------------------------------------------------------
extern "C" void kernel_launch(void* const* d_in, const int* in_sizes, int n_in,
                              void* d_out, int out_size, void* d_ws, size_t ws_size,
                              hipStream_t stream) {
    const float* features = (const float*)d_in[0];
    const int*   resi     = (const int*)d_in[1];
    const int*   chain    = (const int*)d_in[2];
    const int*   batch    = (const int*)d_in[3];
    const int*   nbr      = (const int*)d_in[4];
    const float* W_left   = (const float*)d_in[5];
    const float* W_right  = (const float*)d_in[6];
    const float* W_pos    = (const float*)d_in[7];
    const float* ln_scale = (const float*)d_in[8];
    const float* ln_bias  = (const float*)d_in[9];
    const float* W1       = (const float*)d_in[10];
    const float* b1       = (const float*)d_in[11];
    const float* W2       = (const float*)d_in[12];
    const float* b2       = (const float*)d_in[13];

    // workspace layout (all 16B-aligned):
    char* ws = (char*)d_ws;
    uint4*    leftbf  = (uint4*)ws;                                   // 2 MB
    uint4*    rightbf = (uint4*)(ws + (size_t)N_RES * 64);            // 2 MB
    uint32_t* meta    = (uint32_t*)(ws + (size_t)2 * N_RES * 64);     // 128 KB
    uint32_t* wposbf  = (uint32_t*)(ws + (size_t)2 * N_RES * 64 + N_RES * 4); // 4.2 KB

    float* out_logp = (float*)d_out;
    float* out_dmap = out_logp + (size_t)N_RES * KNEI * NBINS;

    proj_kernel<<<1024, 256, 0, stream>>>(features, W_left, W_right,
                                          resi, chain, batch, W_pos,
                                          leftbf, rightbf, meta, wposbf);
    pair_kernel<<<2048, 256, 0, stream>>>(leftbf, rightbf, meta, nbr, wposbf,
                                          ln_scale, ln_bias, W1, b1, W2, b2,
                                          out_logp, out_dmap);
}

// Round 5
// 334.051 us; speedup vs baseline: 1.1538x; 1.1538x over previous
//
#include <hip/hip_runtime.h>
#include <stdint.h>

// QuickDistogram: N=32768, K=64, C=256, PAIR=32, HID=64, BINS=16, CLIP=32.
// Outputs: log_p [N*K*16] then dmap [N*K] (fp32).
// v4: fp16 packed math (v2) + structural gather reduction: a streaming
// prepass resolves meta[nb] -> 1-byte (rel | same<<7) per pair against the
// 128KB L2-resident meta table.  pair_kernel then has ONE random gather
// (rightbf[nb]) instead of two, and no manual pipeline (v3's backfired:
// FETCH 351->501MB, dur 155->211us).
#define N_RES 32768
#define KNEI  64
#define CFEAT 256
#define PAIRD 32
#define HIDD  64
#define NBINS 16
#define CLIPV 32
#define NPAIRS (N_RES * KNEI)
#define NGROUPS (NPAIRS / 16)         // 131072 groups of 16 pairs

typedef __attribute__((ext_vector_type(2))) _Float16 half2_t;
typedef __attribute__((ext_vector_type(8))) _Float16 half8_t;
typedef __attribute__((ext_vector_type(2))) __fp16   fp16v2;
typedef __attribute__((ext_vector_type(4))) float    float4_t;

union H2U { uint32_t u; half2_t h; fp16v2 f; };
union V4H { uint4 v; uint32_t u[4]; half2_t h2[4]; };
union V8H { uint32_t u[4]; half2_t h2[4]; half8_t h8; };

// pack two fp32 -> fp16x2 (v_cvt_pkrtz_f16_f32, 1 inst). low16 = a, high16 = b.
__device__ __forceinline__ uint32_t pkh(float a, float b) {
    H2U c; c.f = __builtin_amdgcn_cvt_pkrtz(a, b);
    return c.u;
}
__device__ __forceinline__ half2_t pkh2(float a, float b) {
    H2U c; c.f = __builtin_amdgcn_cvt_pkrtz(a, b);
    return c.h;
}

__device__ __forceinline__ float fastrcp(float x) { return __builtin_amdgcn_rcpf(x); }
__device__ __forceinline__ float fexp2(float x)   { return __builtin_amdgcn_exp2f(x); }
__device__ __forceinline__ float flog2(float x)   { return __builtin_amdgcn_logf(x); }

// packed fp16 add through a uint32 (for cross-lane packed reductions)
__device__ __forceinline__ uint32_t addph(uint32_t a, uint32_t b) {
    H2U x, y; x.u = a; y.u = b; x.h = x.h + y.h; return x.u;
}

// tanh-form GELU on 2 packed fp16 values, division- and trans-free.
// Pade(7,6) tanh, rescaled v=(y/4)^2; |y| clamped to 4.5; 1/Nb via
// integer-magic seed + 2 packed Newton steps (~2e-4 rel).
__device__ __forceinline__ half2_t gelu2(half2_t x) {
    const half2_t kA1  = {(_Float16)0.79788456f, (_Float16)0.79788456f};
    const half2_t kA2  = {(_Float16)0.035677408f,(_Float16)0.035677408f};
    const half2_t kPA1 = {(_Float16)2.0512820f,  (_Float16)2.0512820f};
    const half2_t kPA2 = {(_Float16)0.7160840f,  (_Float16)0.7160840f};
    const half2_t kPA3 = {(_Float16)0.0303104f,  (_Float16)0.0303104f};
    const half2_t kPB1 = {(_Float16)7.3846154f,  (_Float16)7.3846154f};
    const half2_t kPB2 = {(_Float16)5.9673660f,  (_Float16)5.9673660f};
    const half2_t kPB3 = {(_Float16)0.8486920f,  (_Float16)0.8486920f};
    const half2_t kOne = {(_Float16)1.0f,  (_Float16)1.0f};
    const half2_t kTwo = {(_Float16)2.0f,  (_Float16)2.0f};
    const half2_t kQtr = {(_Float16)0.25f, (_Float16)0.25f};
    const half2_t kHlf = {(_Float16)0.5f,  (_Float16)0.5f};
    const half2_t kClp = {(_Float16)4.5f,  (_Float16)4.5f};
    const half2_t kNCl = {(_Float16)-4.5f, (_Float16)-4.5f};

    half2_t u0 = x * x;
    half2_t y  = x * __builtin_elementwise_fma(kA2, u0, kA1);
    y = __builtin_elementwise_min(__builtin_elementwise_max(y, kNCl), kClp);
    half2_t yq = y * kQtr;
    half2_t v  = yq * yq;                      // v = (y/4)^2 <= 1.266
    half2_t pa = __builtin_elementwise_fma(kPA3, v, kPA2);
    pa = __builtin_elementwise_fma(pa, v, kPA1);
    pa = __builtin_elementwise_fma(pa, v, kOne);
    half2_t pb = __builtin_elementwise_fma(kPB3, v, kPB2);
    pb = __builtin_elementwise_fma(pb, v, kPB1);
    pb = __builtin_elementwise_fma(pb, v, kOne); // pb in [1, 21.7]
    half2_t a = y * pa;
    H2U cb, cr;
    cb.h = pb;
    cr.u = 0x78007800u - cb.u;                 // packed reciprocal seed
    half2_t r = cr.h;
    r = r * __builtin_elementwise_fma(-pb, r, kTwo);
    r = r * __builtin_elementwise_fma(-pb, r, kTwo);
    half2_t th = a * r;
    half2_t hx = x * kHlf;
    return __builtin_elementwise_fma(hx, th, hx);
}

// ---------------------------------------------------------------------------
// Kernel 1: left/right = feat @ W_{l,r} (fp32 VALU) -> fp16 tables, packed
// meta dword, fp16 wpos table.  grid=1024: blocks 0..511 do LEFT (and meta),
// 512..1023 do RIGHT.  32KB LDS/block -> 4 blocks/CU.
// ---------------------------------------------------------------------------
__global__ __launch_bounds__(256) void proj_kernel(
    const float* __restrict__ feat, const float* __restrict__ Wl,
    const float* __restrict__ Wr, const int* __restrict__ resi,
    const int* __restrict__ chain, const int* __restrict__ batch,
    const float* __restrict__ wpos,
    uint4* __restrict__ leftbf, uint4* __restrict__ rightbf,
    uint32_t* __restrict__ meta, uint32_t* __restrict__ wposbf)
{
    __shared__ __align__(16) float Wc[CFEAT * 32];   // 32 KB
    const int tid   = threadIdx.x;
    const int half  = blockIdx.x >> 9;               // 0 = left, 1 = right
    const int rb    = (blockIdx.x & 511) * 64;
    const float* W  = half ? Wr : Wl;
    uint4* outtb    = half ? rightbf : leftbf;

    for (int idx = tid; idx < CFEAT * 32; idx += 256)
        Wc[idx] = W[idx];
    if (half == 0 && tid < 64) {
        int r = rb + tid;
        meta[r] = (uint32_t)resi[r] | ((uint32_t)chain[r] << 16)
                | ((uint32_t)batch[r] << 19);
    }
    if (blockIdx.x == 0) {
        for (int i = tid; i < (2 * CLIPV + 1) * PAIRD / 2; i += 256)
            wposbf[i] = pkh(wpos[2 * i], wpos[2 * i + 1]);
    }
    __syncthreads();

    const int cb  = (tid & 3) * 8;        // 8 of 32 output cols
    const int row = rb + (tid >> 2);      // 1 row

    float acc[8];
#pragma unroll
    for (int j = 0; j < 8; ++j) acc[j] = 0.f;

    for (int i = 0; i < CFEAT; i += 4) {
        float4_t f = *(const float4_t*)(feat + (size_t)row * CFEAT + i);
#pragma unroll
        for (int s = 0; s < 4; ++s) {
            float4_t wa = *(const float4_t*)(Wc + (i + s) * 32 + cb);
            float4_t wb = *(const float4_t*)(Wc + (i + s) * 32 + cb + 4);
#pragma unroll
            for (int j = 0; j < 4; ++j) {
                acc[j]     = __builtin_fmaf(f[s], wa[j], acc[j]);
                acc[4 + j] = __builtin_fmaf(f[s], wb[j], acc[4 + j]);
            }
        }
    }
    uint2 o, o2;
    o.x  = pkh(acc[0], acc[1]);
    o.y  = pkh(acc[2], acc[3]);
    o2.x = pkh(acc[4], acc[5]);
    o2.y = pkh(acc[6], acc[7]);
    uint2* dst = (uint2*)outtb + (size_t)row * 8 + (cb >> 2);
    dst[0] = o;
    dst[1] = o2;
}

// ---------------------------------------------------------------------------
// Kernel 1.5: streaming prepass — resolve the meta[nb] gather against the
// 128KB (trivially L2-resident) meta table and emit 1 byte per pair:
// rel (7 bits) | same (bit 7).  All other traffic coalesced streams.
// ---------------------------------------------------------------------------
__global__ __launch_bounds__(256) void prepass_kernel(
    const int* __restrict__ nbr, const uint32_t* __restrict__ meta,
    unsigned char* __restrict__ rs)
{
    const int p  = blockIdx.x * 256 + threadIdx.x;
    const int nb = __builtin_nontemporal_load(nbr + p);
    const uint32_t mn = meta[p >> 6];        // broadcast within 64 threads
    const uint32_t mb = meta[nb];            // gather into 128KB table
    const int rel = min(max((int)(mb & 0xFFFFu) - (int)(mn & 0xFFFFu),
                            -CLIPV), CLIPV) + CLIPV;
    const unsigned int same = (((mb ^ mn) & 0xFFFF0000u) == 0u) ? 0x80u : 0u;
    __builtin_nontemporal_store((unsigned char)(rel | same), rs + p);
}

// ---------------------------------------------------------------------------
// Kernel 2: per-pair dcode -> LN -> MLP(MFMA f16) -> log_softmax -> outputs.
// One wave = 16 pairs; lane (q=lane>>4, c=lane&15) holds dims 8q..8q+7 of
// pair c.  Packed fp16 math; single random gather (rightbf[nb]).
// ---------------------------------------------------------------------------
__global__ __launch_bounds__(256, 8) void pair_kernel(
    const uint4* __restrict__ leftbf, const uint4* __restrict__ rightbf,
    const unsigned char* __restrict__ rs, const int* __restrict__ nbr,
    const uint32_t* __restrict__ wposbf,
    const float* __restrict__ lnS, const float* __restrict__ lnB,
    const float* __restrict__ W1, const float* __restrict__ b1,
    const float* __restrict__ W2, const float* __restrict__ b2,
    float* __restrict__ out_logp, float* __restrict__ out_dmap)
{
    __shared__ __align__(16) unsigned char Hbuf[4][16 * 144]; // wave-private H transpose
    __shared__ __align__(16) float b1p[HIDD];                 // b1 + lnB @ W1 (fp32)

    const int tid    = threadIdx.x;
    const int lane   = tid & 63;
    const int wlocal = tid >> 6;
    const int q      = lane >> 4;
    const int c      = lane & 15;

    // ---- preamble: fold ln_bias through W1 into b1' ----
    if (tid < HIDD) {
        float s = b1[tid];
        for (int k = 0; k < PAIRD; ++k)
            s = __builtin_fmaf(lnB[k], W1[k * HIDD + tid], s);
        b1p[tid] = s;
    }

    // ---- weight fragments: W1' = diag(ln_scale) @ W1, A-frag of W1'^T (fp16) ----
    half8_t w1a[4];
#pragma unroll
    for (int t = 0; t < 4; ++t) {
        V8H tmp;
#pragma unroll
        for (int v = 0; v < 4; ++v) {
            int k0 = q * 8 + 2 * v, k1 = k0 + 1;
            float a0 = lnS[k0] * W1[k0 * HIDD + 16 * t + c];
            float a1 = lnS[k1] * W1[k1 * HIDD + 16 * t + c];
            tmp.u[v] = pkh(a0, a1);
        }
        w1a[t] = tmp.h8;
    }
    half8_t w2a[2];                        // A-frag of W2^T, K-tile kt (fp16)
#pragma unroll
    for (int kt = 0; kt < 2; ++kt) {
        V8H tmp;
#pragma unroll
        for (int v = 0; v < 4; ++v) {
            int k0 = kt * 32 + q * 8 + 2 * v;
            tmp.u[v] = pkh(W2[k0 * NBINS + c], W2[(k0 + 1) * NBINS + c]);
        }
        w2a[kt] = tmp.h8;
    }
    const float4_t b2f = *(const float4_t*)(b2 + 4 * q);   // C-init for layer 2

    __syncthreads();   // b1p ready

    const int wglobal = (blockIdx.x * 256 + tid) >> 6;
    const int nwaves  = (gridDim.x * 256) >> 6;

    for (int g = wglobal; g < NGROUPS; g += nwaves) {
        const int pbase = g * 16;
        const int n = pbase >> 6;             // 4 groups per residue n
        const int p = pbase + c;

        const int nb = __builtin_nontemporal_load(nbr + p);
        const unsigned int rsb = __builtin_nontemporal_load(rs + p);
        const uint4 lf = leftbf [(size_t)n  * 4 + q];   // broadcast 64B/wave
        const uint4 rf = rightbf[(size_t)nb * 4 + q];   // 1 line per pair (gather)

        const int rel = rsb & 0x7Fu;
        const uint32_t mskbits = (rsb & 0x80u) ? 0x3C003C00u : 0u;  // half2(1,1)/(0,0)
        const uint4 pw = *(const uint4*)(wposbf + rel * 16 + q * 4); // 4KB L1-res

        // ---- dcode dims 8q..8q+7 of pair c, packed fp16 ----
        V4H lu, ru, pu; lu.v = lf; ru.v = rf; pu.v = pw;
        H2U mm; mm.u = mskbits;
        const half2_t m2 = mm.h;
        half2_t d2[4];
#pragma unroll
        for (int v = 0; v < 4; ++v)
            d2[v] = __builtin_elementwise_fma(pu.h2[v], m2, lu.h2[v] + ru.h2[v]);

        // ---- LayerNorm stats over 32 dims (packed partial sums) ----
        half2_t a1 = (d2[0] + d2[1]) + (d2[2] + d2[3]);
        half2_t aq = __builtin_elementwise_fma(d2[0], d2[0],
                     __builtin_elementwise_fma(d2[1], d2[1],
                     __builtin_elementwise_fma(d2[2], d2[2], d2[3] * d2[3])));
        H2U c1, c2; c1.h = a1; c2.h = aq;
        uint32_t s1p = c1.u, s2p = c2.u;
        s1p = addph(s1p, (uint32_t)__shfl_xor((int)s1p, 16, 64));
        s1p = addph(s1p, (uint32_t)__shfl_xor((int)s1p, 32, 64));
        s2p = addph(s2p, (uint32_t)__shfl_xor((int)s2p, 16, 64));
        s2p = addph(s2p, (uint32_t)__shfl_xor((int)s2p, 32, 64));
        H2U f1, f2; f1.u = s1p; f2.u = s2p;
        const float s1 = (float)f1.h[0] + (float)f1.h[1];
        const float s2 = (float)f2.h[0] + (float)f2.h[1];
        const float mu   = s1 * (1.0f / 32.0f);
        const float var  = __builtin_fmaf(-mu, mu, s2 * (1.0f / 32.0f));
        const float rstd = __builtin_amdgcn_rsqf(var + 1e-5f);
        const float sh   = -mu * rstd;

        const half2_t rs2 = pkh2(rstd, rstd);
        const half2_t sh2 = pkh2(sh, sh);
        V8H dn;
#pragma unroll
        for (int v = 0; v < 4; ++v)
            dn.h2[v] = __builtin_elementwise_fma(d2[v], rs2, sh2);
        const half8_t dfrag = dn.h8;     // B-frag: B[k=q*8+j][n=c]

        // ---- layer 1 (bias b1' as MFMA C operand, broadcast LDS read) ----
        float4_t hacc[4];
#pragma unroll
        for (int t = 0; t < 4; ++t) {
            float4_t c1v = *(const float4_t*)(b1p + 16 * t + 4 * q);
            hacc[t] = __builtin_amdgcn_mfma_f32_16x16x32_f16(w1a[t], dfrag, c1v, 0, 0, 0);
        }

        // ---- GELU (packed fp16) + store to LDS (transpose to layer-2 B-frag) ----
        unsigned char* hb = &Hbuf[wlocal][0] + c * 144;
#pragma unroll
        for (int t = 0; t < 4; ++t) {
            half2_t g01 = gelu2(pkh2(hacc[t][0], hacc[t][1]));
            half2_t g23 = gelu2(pkh2(hacc[t][2], hacc[t][3]));
            union { half2_t h[2]; uint2 u2; } w;
            w.h[0] = g01; w.h[1] = g23;
            *(uint2*)(hb + 32 * t + 8 * q) = w.u2;   // hid 16t+4q+0..3 of pair c
        }
        const half8_t hf0 = *(const half8_t*)(hb + 16 * q);        // hid 8q..8q+7
        const half8_t hf1 = *(const half8_t*)(hb + 64 + 16 * q);   // hid 32+8q..

        // ---- layer 2 (b2 as C operand): lane holds bins 4q..4q+3 of pair c ----
        float4_t lacc;
        lacc = __builtin_amdgcn_mfma_f32_16x16x32_f16(w2a[0], hf0, b2f,  0, 0, 0);
        lacc = __builtin_amdgcn_mfma_f32_16x16x32_f16(w2a[1], hf1, lacc, 0, 0, 0);

        // ---- log-softmax without max-subtraction (logits are O(+-10)) ----
        const float LOG2E = 1.4426950408889634f, LN2 = 0.6931471805599453f;
        float e[4];
#pragma unroll
        for (int r = 0; r < 4; ++r) e[r] = fexp2(lacc[r] * LOG2E);
        float ssum = (e[0] + e[1]) + (e[2] + e[3]);
        ssum += __shfl_xor(ssum, 16, 64);
        ssum += __shfl_xor(ssum, 32, 64);
        const float lse = flog2(ssum) * LN2;

        // ---- NT stores: bypass/no-allocate L2, keep it for the gathers ----
        float4_t lp = {lacc[0] - lse, lacc[1] - lse, lacc[2] - lse, lacc[3] - lse};
        __builtin_nontemporal_store(lp, (float4_t*)(out_logp + (size_t)p * NBINS + 4 * q));

        const float step  = 22.0f / NBINS;
        const float cbase = (4 * q + 0.5f) * step;
        float dpart = e[0] * cbase + e[1] * (cbase + step)
                    + e[2] * (cbase + 2 * step) + e[3] * (cbase + 3 * step);
        dpart += __shfl_xor(dpart, 16, 64);
        dpart += __shfl_xor(dpart, 32, 64);
        if (q == 0)
            __builtin_nontemporal_store(dpart * fastrcp(ssum), out_dmap + p);
    }
}

// ---------------------------------------------------------------------------
extern "C" void kernel_launch(void* const* d_in, const int* in_sizes, int n_in,
                              void* d_out, int out_size, void* d_ws, size_t ws_size,
                              hipStream_t stream) {
    const float* features = (const float*)d_in[0];
    const int*   resi     = (const int*)d_in[1];
    const int*   chain    = (const int*)d_in[2];
    const int*   batch    = (const int*)d_in[3];
    const int*   nbr      = (const int*)d_in[4];
    const float* W_left   = (const float*)d_in[5];
    const float* W_right  = (const float*)d_in[6];
    const float* W_pos    = (const float*)d_in[7];
    const float* ln_scale = (const float*)d_in[8];
    const float* ln_bias  = (const float*)d_in[9];
    const float* W1       = (const float*)d_in[10];
    const float* b1       = (const float*)d_in[11];
    const float* W2       = (const float*)d_in[12];
    const float* b2       = (const float*)d_in[13];

    // workspace layout (16B-aligned; total ~6.4 MB):
    char* ws = (char*)d_ws;
    uint4*         leftbf  = (uint4*)ws;                                   // 2 MB
    uint4*         rightbf = (uint4*)(ws + (size_t)N_RES * 64);            // 2 MB
    uint32_t*      meta    = (uint32_t*)(ws + (size_t)2 * N_RES * 64);     // 128 KB
    uint32_t*      wposbf  = (uint32_t*)(ws + (size_t)2 * N_RES * 64 + N_RES * 4); // 4.2 KB
    unsigned char* rs      = (unsigned char*)(ws + (size_t)2 * N_RES * 64
                                              + N_RES * 4 + 8192);         // 2 MB

    float* out_logp = (float*)d_out;
    float* out_dmap = out_logp + (size_t)N_RES * KNEI * NBINS;

    proj_kernel<<<1024, 256, 0, stream>>>(features, W_left, W_right,
                                          resi, chain, batch, W_pos,
                                          leftbf, rightbf, meta, wposbf);
    prepass_kernel<<<NPAIRS / 256, 256, 0, stream>>>(nbr, meta, rs);
    pair_kernel<<<2048, 256, 0, stream>>>(leftbf, rightbf, rs, nbr, wposbf,
                                          ln_scale, ln_bias, W1, b1, W2, b2,
                                          out_logp, out_dmap);
}

// Round 7
// 320.078 us; speedup vs baseline: 1.2042x; 1.0437x over previous
//
#include <hip/hip_runtime.h>
#include <stdint.h>

// QuickDistogram: N=32768, K=64, C=256, PAIR=32, HID=64, BINS=16, CLIP=32.
// Outputs: log_p [N*K*16] then dmap [N*K] (fp32).
// v6 = v4 (correct builtin-NT stores; sc1 asm stores corrupted via L2
// dirty-line writeback — reverted) + dual-group iterations: wave j handles
// groups 2j,2j+1 (same residue n -> shared left load), issuing BOTH rightbf
// gathers up front so group-A's MLP (~600cy) hides group-B's gather latency.
// Targets the measured latency/MLP limit (VALU 42%, HBM 44%, neither
// saturated).  launch_bounds(256,6) gives VGPR room to keep gathers hoisted.
#define N_RES 32768
#define KNEI  64
#define CFEAT 256
#define PAIRD 32
#define HIDD  64
#define NBINS 16
#define CLIPV 32
#define NPAIRS (N_RES * KNEI)
#define NGROUPS (NPAIRS / 16)         // 131072 groups of 16 pairs
#define NJOBS   (NGROUPS / 2)         // 65536 dual-group jobs

typedef __attribute__((ext_vector_type(2))) _Float16 half2_t;
typedef __attribute__((ext_vector_type(8))) _Float16 half8_t;
typedef __attribute__((ext_vector_type(2))) __fp16   fp16v2;
typedef __attribute__((ext_vector_type(4))) float    float4_t;

union H2U { uint32_t u; half2_t h; fp16v2 f; };
union V4H { uint4 v; uint32_t u[4]; half2_t h2[4]; };
union V8H { uint32_t u[4]; half2_t h2[4]; half8_t h8; };

// pack two fp32 -> fp16x2 (v_cvt_pkrtz_f16_f32, 1 inst). low16 = a, high16 = b.
__device__ __forceinline__ uint32_t pkh(float a, float b) {
    H2U c; c.f = __builtin_amdgcn_cvt_pkrtz(a, b);
    return c.u;
}
__device__ __forceinline__ half2_t pkh2(float a, float b) {
    H2U c; c.f = __builtin_amdgcn_cvt_pkrtz(a, b);
    return c.h;
}

__device__ __forceinline__ float fastrcp(float x) { return __builtin_amdgcn_rcpf(x); }
__device__ __forceinline__ float fexp2(float x)   { return __builtin_amdgcn_exp2f(x); }
__device__ __forceinline__ float flog2(float x)   { return __builtin_amdgcn_logf(x); }

// packed fp16 add through a uint32 (for cross-lane packed reductions)
__device__ __forceinline__ uint32_t addph(uint32_t a, uint32_t b) {
    H2U x, y; x.u = a; y.u = b; x.h = x.h + y.h; return x.u;
}

// tanh-form GELU on 2 packed fp16 values, division- and trans-free.
// Pade(7,6) tanh, rescaled v=(y/4)^2; |y| clamped to 4.5; 1/Nb via
// integer-magic seed + 2 packed Newton steps (~2e-4 rel).
__device__ __forceinline__ half2_t gelu2(half2_t x) {
    const half2_t kA1  = {(_Float16)0.79788456f, (_Float16)0.79788456f};
    const half2_t kA2  = {(_Float16)0.035677408f,(_Float16)0.035677408f};
    const half2_t kPA1 = {(_Float16)2.0512820f,  (_Float16)2.0512820f};
    const half2_t kPA2 = {(_Float16)0.7160840f,  (_Float16)0.7160840f};
    const half2_t kPA3 = {(_Float16)0.0303104f,  (_Float16)0.0303104f};
    const half2_t kPB1 = {(_Float16)7.3846154f,  (_Float16)7.3846154f};
    const half2_t kPB2 = {(_Float16)5.9673660f,  (_Float16)5.9673660f};
    const half2_t kPB3 = {(_Float16)0.8486920f,  (_Float16)0.8486920f};
    const half2_t kOne = {(_Float16)1.0f,  (_Float16)1.0f};
    const half2_t kTwo = {(_Float16)2.0f,  (_Float16)2.0f};
    const half2_t kQtr = {(_Float16)0.25f, (_Float16)0.25f};
    const half2_t kHlf = {(_Float16)0.5f,  (_Float16)0.5f};
    const half2_t kClp = {(_Float16)4.5f,  (_Float16)4.5f};
    const half2_t kNCl = {(_Float16)-4.5f, (_Float16)-4.5f};

    half2_t u0 = x * x;
    half2_t y  = x * __builtin_elementwise_fma(kA2, u0, kA1);
    y = __builtin_elementwise_min(__builtin_elementwise_max(y, kNCl), kClp);
    half2_t yq = y * kQtr;
    half2_t v  = yq * yq;                      // v = (y/4)^2 <= 1.266
    half2_t pa = __builtin_elementwise_fma(kPA3, v, kPA2);
    pa = __builtin_elementwise_fma(pa, v, kPA1);
    pa = __builtin_elementwise_fma(pa, v, kOne);
    half2_t pb = __builtin_elementwise_fma(kPB3, v, kPB2);
    pb = __builtin_elementwise_fma(pb, v, kPB1);
    pb = __builtin_elementwise_fma(pb, v, kOne); // pb in [1, 21.7]
    half2_t a = y * pa;
    H2U cb, cr;
    cb.h = pb;
    cr.u = 0x78007800u - cb.u;                 // packed reciprocal seed
    half2_t r = cr.h;
    r = r * __builtin_elementwise_fma(-pb, r, kTwo);
    r = r * __builtin_elementwise_fma(-pb, r, kTwo);
    half2_t th = a * r;
    half2_t hx = x * kHlf;
    return __builtin_elementwise_fma(hx, th, hx);
}

// ---------------------------------------------------------------------------
// Kernel 1: left/right = feat @ W_{l,r} (fp32 VALU) -> fp16 tables, packed
// meta dword, fp16 wpos table.  grid=1024: blocks 0..511 do LEFT (and meta),
// 512..1023 do RIGHT.  32KB LDS/block -> 4 blocks/CU.
// ---------------------------------------------------------------------------
__global__ __launch_bounds__(256) void proj_kernel(
    const float* __restrict__ feat, const float* __restrict__ Wl,
    const float* __restrict__ Wr, const int* __restrict__ resi,
    const int* __restrict__ chain, const int* __restrict__ batch,
    const float* __restrict__ wpos,
    uint4* __restrict__ leftbf, uint4* __restrict__ rightbf,
    uint32_t* __restrict__ meta, uint32_t* __restrict__ wposbf)
{
    __shared__ __align__(16) float Wc[CFEAT * 32];   // 32 KB
    const int tid   = threadIdx.x;
    const int half  = blockIdx.x >> 9;               // 0 = left, 1 = right
    const int rb    = (blockIdx.x & 511) * 64;
    const float* W  = half ? Wr : Wl;
    uint4* outtb    = half ? rightbf : leftbf;

    for (int idx = tid; idx < CFEAT * 32; idx += 256)
        Wc[idx] = W[idx];
    if (half == 0 && tid < 64) {
        int r = rb + tid;
        meta[r] = (uint32_t)resi[r] | ((uint32_t)chain[r] << 16)
                | ((uint32_t)batch[r] << 19);
    }
    if (blockIdx.x == 0) {
        for (int i = tid; i < (2 * CLIPV + 1) * PAIRD / 2; i += 256)
            wposbf[i] = pkh(wpos[2 * i], wpos[2 * i + 1]);
    }
    __syncthreads();

    const int cb  = (tid & 3) * 8;        // 8 of 32 output cols
    const int row = rb + (tid >> 2);      // 1 row

    float acc[8];
#pragma unroll
    for (int j = 0; j < 8; ++j) acc[j] = 0.f;

    for (int i = 0; i < CFEAT; i += 4) {
        float4_t f = *(const float4_t*)(feat + (size_t)row * CFEAT + i);
#pragma unroll
        for (int s = 0; s < 4; ++s) {
            float4_t wa = *(const float4_t*)(Wc + (i + s) * 32 + cb);
            float4_t wb = *(const float4_t*)(Wc + (i + s) * 32 + cb + 4);
#pragma unroll
            for (int j = 0; j < 4; ++j) {
                acc[j]     = __builtin_fmaf(f[s], wa[j], acc[j]);
                acc[4 + j] = __builtin_fmaf(f[s], wb[j], acc[4 + j]);
            }
        }
    }
    uint2 o, o2;
    o.x  = pkh(acc[0], acc[1]);
    o.y  = pkh(acc[2], acc[3]);
    o2.x = pkh(acc[4], acc[5]);
    o2.y = pkh(acc[6], acc[7]);
    uint2* dst = (uint2*)outtb + (size_t)row * 8 + (cb >> 2);
    dst[0] = o;
    dst[1] = o2;
}

// ---------------------------------------------------------------------------
// Kernel 1.5: streaming prepass — resolve the meta[nb] gather against the
// 128KB (trivially L2-resident) meta table and emit 1 byte per pair:
// rel (7 bits) | same (bit 7).  All other traffic coalesced streams.
// ---------------------------------------------------------------------------
__global__ __launch_bounds__(256) void prepass_kernel(
    const int* __restrict__ nbr, const uint32_t* __restrict__ meta,
    unsigned char* __restrict__ rs)
{
    const int p  = blockIdx.x * 256 + threadIdx.x;
    const int nb = __builtin_nontemporal_load(nbr + p);
    const uint32_t mn = meta[p >> 6];        // broadcast within 64 threads
    const uint32_t mb = meta[nb];            // gather into 128KB table
    const int rel = min(max((int)(mb & 0xFFFFu) - (int)(mn & 0xFFFFu),
                            -CLIPV), CLIPV) + CLIPV;
    const unsigned int same = (((mb ^ mn) & 0xFFFF0000u) == 0u) ? 0x80u : 0u;
    __builtin_nontemporal_store((unsigned char)(rel | same), rs + p);
}

// ---------------------------------------------------------------------------
// Kernel 2: per-pair dcode -> LN -> MLP(MFMA f16) -> log_softmax -> outputs.
// One wave = 2 groups of 16 pairs (same residue n); lane (q=lane>>4,
// c=lane&15) holds dims 8q..8q+7 of pair c.  Both rightbf gathers issue
// up-front; packed fp16 math throughout.
// ---------------------------------------------------------------------------
__global__ __launch_bounds__(256, 6) void pair_kernel(
    const uint4* __restrict__ leftbf, const uint4* __restrict__ rightbf,
    const unsigned char* __restrict__ rs, const int* __restrict__ nbr,
    const uint32_t* __restrict__ wposbf,
    const float* __restrict__ lnS, const float* __restrict__ lnB,
    const float* __restrict__ W1, const float* __restrict__ b1,
    const float* __restrict__ W2, const float* __restrict__ b2,
    float* __restrict__ out_logp, float* __restrict__ out_dmap)
{
    __shared__ __align__(16) unsigned char Hbuf[4][2][16 * 144]; // wave-private H transpose x2
    __shared__ __align__(16) float b1p[HIDD];                    // b1 + lnB @ W1 (fp32)

    const int tid    = threadIdx.x;
    const int lane   = tid & 63;
    const int wlocal = tid >> 6;
    const int q      = lane >> 4;
    const int c      = lane & 15;

    // ---- preamble: fold ln_bias through W1 into b1' ----
    if (tid < HIDD) {
        float s = b1[tid];
        for (int k = 0; k < PAIRD; ++k)
            s = __builtin_fmaf(lnB[k], W1[k * HIDD + tid], s);
        b1p[tid] = s;
    }

    // ---- weight fragments: W1' = diag(ln_scale) @ W1, A-frag of W1'^T (fp16) ----
    half8_t w1a[4];
#pragma unroll
    for (int t = 0; t < 4; ++t) {
        V8H tmp;
#pragma unroll
        for (int v = 0; v < 4; ++v) {
            int k0 = q * 8 + 2 * v, k1 = k0 + 1;
            float a0 = lnS[k0] * W1[k0 * HIDD + 16 * t + c];
            float a1 = lnS[k1] * W1[k1 * HIDD + 16 * t + c];
            tmp.u[v] = pkh(a0, a1);
        }
        w1a[t] = tmp.h8;
    }
    half8_t w2a[2];                        // A-frag of W2^T, K-tile kt (fp16)
#pragma unroll
    for (int kt = 0; kt < 2; ++kt) {
        V8H tmp;
#pragma unroll
        for (int v = 0; v < 4; ++v) {
            int k0 = kt * 32 + q * 8 + 2 * v;
            tmp.u[v] = pkh(W2[k0 * NBINS + c], W2[(k0 + 1) * NBINS + c]);
        }
        w2a[kt] = tmp.h8;
    }
    const float4_t b2f = *(const float4_t*)(b2 + 4 * q);   // C-init for layer 2

    __syncthreads();   // b1p ready

    // per-group MLP + log-softmax + stores (wave-private, no barriers)
    auto process = [&](uint4 lfv, uint4 rfv, uint4 pwv, unsigned int samebit,
                       int p, unsigned char* hb) {
        V4H lu, ru, pu; lu.v = lfv; ru.v = rfv; pu.v = pwv;
        H2U mm; mm.u = samebit ? 0x3C003C00u : 0u;
        const half2_t m2 = mm.h;
        half2_t d2[4];
#pragma unroll
        for (int v = 0; v < 4; ++v)
            d2[v] = __builtin_elementwise_fma(pu.h2[v], m2, lu.h2[v] + ru.h2[v]);

        // ---- LayerNorm stats over 32 dims (packed partial sums) ----
        half2_t a1 = (d2[0] + d2[1]) + (d2[2] + d2[3]);
        half2_t aq = __builtin_elementwise_fma(d2[0], d2[0],
                     __builtin_elementwise_fma(d2[1], d2[1],
                     __builtin_elementwise_fma(d2[2], d2[2], d2[3] * d2[3])));
        H2U c1, c2; c1.h = a1; c2.h = aq;
        uint32_t s1p = c1.u, s2p = c2.u;
        s1p = addph(s1p, (uint32_t)__shfl_xor((int)s1p, 16, 64));
        s1p = addph(s1p, (uint32_t)__shfl_xor((int)s1p, 32, 64));
        s2p = addph(s2p, (uint32_t)__shfl_xor((int)s2p, 16, 64));
        s2p = addph(s2p, (uint32_t)__shfl_xor((int)s2p, 32, 64));
        H2U f1, f2; f1.u = s1p; f2.u = s2p;
        const float s1 = (float)f1.h[0] + (float)f1.h[1];
        const float s2 = (float)f2.h[0] + (float)f2.h[1];
        const float mu   = s1 * (1.0f / 32.0f);
        const float var  = __builtin_fmaf(-mu, mu, s2 * (1.0f / 32.0f));
        const float rstd = __builtin_amdgcn_rsqf(var + 1e-5f);
        const float sh   = -mu * rstd;

        const half2_t rs2 = pkh2(rstd, rstd);
        const half2_t sh2 = pkh2(sh, sh);
        V8H dn;
#pragma unroll
        for (int v = 0; v < 4; ++v)
            dn.h2[v] = __builtin_elementwise_fma(d2[v], rs2, sh2);
        const half8_t dfrag = dn.h8;     // B-frag: B[k=q*8+j][n=c]

        // ---- layer 1 (bias b1' as MFMA C operand, broadcast LDS read) ----
        float4_t hacc[4];
#pragma unroll
        for (int t = 0; t < 4; ++t) {
            float4_t c1v = *(const float4_t*)(b1p + 16 * t + 4 * q);
            hacc[t] = __builtin_amdgcn_mfma_f32_16x16x32_f16(w1a[t], dfrag, c1v, 0, 0, 0);
        }

        // ---- GELU (packed fp16) + store to LDS (transpose to layer-2 B-frag) ----
#pragma unroll
        for (int t = 0; t < 4; ++t) {
            half2_t g01 = gelu2(pkh2(hacc[t][0], hacc[t][1]));
            half2_t g23 = gelu2(pkh2(hacc[t][2], hacc[t][3]));
            union { half2_t h[2]; uint2 u2; } w;
            w.h[0] = g01; w.h[1] = g23;
            *(uint2*)(hb + 32 * t + 8 * q) = w.u2;   // hid 16t+4q+0..3 of pair c
        }
        const half8_t hf0 = *(const half8_t*)(hb + 16 * q);        // hid 8q..8q+7
        const half8_t hf1 = *(const half8_t*)(hb + 64 + 16 * q);   // hid 32+8q..

        // ---- layer 2 (b2 as C operand): lane holds bins 4q..4q+3 of pair c ----
        float4_t lacc;
        lacc = __builtin_amdgcn_mfma_f32_16x16x32_f16(w2a[0], hf0, b2f,  0, 0, 0);
        lacc = __builtin_amdgcn_mfma_f32_16x16x32_f16(w2a[1], hf1, lacc, 0, 0, 0);

        // ---- log-softmax without max-subtraction (logits are O(+-10)) ----
        const float LOG2E = 1.4426950408889634f, LN2 = 0.6931471805599453f;
        float e[4];
#pragma unroll
        for (int r = 0; r < 4; ++r) e[r] = fexp2(lacc[r] * LOG2E);
        float ssum = (e[0] + e[1]) + (e[2] + e[3]);
        ssum += __shfl_xor(ssum, 16, 64);
        ssum += __shfl_xor(ssum, 32, 64);
        const float lse = flog2(ssum) * LN2;

        // ---- NT stores (builtin: nt hint only — sc1 bypass corrupts) ----
        float4_t lp = {lacc[0] - lse, lacc[1] - lse, lacc[2] - lse, lacc[3] - lse};
        __builtin_nontemporal_store(lp, (float4_t*)(out_logp + (size_t)p * NBINS + 4 * q));

        const float step  = 22.0f / NBINS;
        const float cbase = (4 * q + 0.5f) * step;
        float dpart = e[0] * cbase + e[1] * (cbase + step)
                    + e[2] * (cbase + 2 * step) + e[3] * (cbase + 3 * step);
        dpart += __shfl_xor(dpart, 16, 64);
        dpart += __shfl_xor(dpart, 32, 64);
        if (q == 0)
            __builtin_nontemporal_store(dpart * fastrcp(ssum), out_dmap + p);
    };

    const int wglobal = (blockIdx.x * 256 + tid) >> 6;
    const int nwaves  = (gridDim.x * 256) >> 6;

    for (int j = wglobal; j < NJOBS; j += nwaves) {
        // groups 2j and 2j+1 always share residue n = j>>1
        const int n  = j >> 1;
        const int p0 = j * 32 + c;
        const int p1 = p0 + 16;

        // issue all loads up front: both gathers in flight together
        const int nb0 = __builtin_nontemporal_load(nbr + p0);
        const int nb1 = __builtin_nontemporal_load(nbr + p1);
        const unsigned int rsA = __builtin_nontemporal_load(rs + p0);
        const unsigned int rsB = __builtin_nontemporal_load(rs + p1);
        const uint4 lf  = leftbf [(size_t)n   * 4 + q];   // shared, broadcast
        const uint4 rfA = rightbf[(size_t)nb0 * 4 + q];   // random gather A
        const uint4 rfB = rightbf[(size_t)nb1 * 4 + q];   // random gather B
        const uint4 pwA = *(const uint4*)(wposbf + (rsA & 0x7Fu) * 16 + q * 4);
        const uint4 pwB = *(const uint4*)(wposbf + (rsB & 0x7Fu) * 16 + q * 4);

        process(lf, rfA, pwA, rsA & 0x80u, p0, &Hbuf[wlocal][0][0] + c * 144);
        process(lf, rfB, pwB, rsB & 0x80u, p1, &Hbuf[wlocal][1][0] + c * 144);
    }
}

// ---------------------------------------------------------------------------
extern "C" void kernel_launch(void* const* d_in, const int* in_sizes, int n_in,
                              void* d_out, int out_size, void* d_ws, size_t ws_size,
                              hipStream_t stream) {
    const float* features = (const float*)d_in[0];
    const int*   resi     = (const int*)d_in[1];
    const int*   chain    = (const int*)d_in[2];
    const int*   batch    = (const int*)d_in[3];
    const int*   nbr      = (const int*)d_in[4];
    const float* W_left   = (const float*)d_in[5];
    const float* W_right  = (const float*)d_in[6];
    const float* W_pos    = (const float*)d_in[7];
    const float* ln_scale = (const float*)d_in[8];
    const float* ln_bias  = (const float*)d_in[9];
    const float* W1       = (const float*)d_in[10];
    const float* b1       = (const float*)d_in[11];
    const float* W2       = (const float*)d_in[12];
    const float* b2       = (const float*)d_in[13];

    // workspace layout (16B-aligned; total ~6.4 MB):
    char* ws = (char*)d_ws;
    uint4*         leftbf  = (uint4*)ws;                                   // 2 MB
    uint4*         rightbf = (uint4*)(ws + (size_t)N_RES * 64);            // 2 MB
    uint32_t*      meta    = (uint32_t*)(ws + (size_t)2 * N_RES * 64);     // 128 KB
    uint32_t*      wposbf  = (uint32_t*)(ws + (size_t)2 * N_RES * 64 + N_RES * 4); // 4.2 KB
    unsigned char* rs      = (unsigned char*)(ws + (size_t)2 * N_RES * 64
                                              + N_RES * 4 + 8192);         // 2 MB

    float* out_logp = (float*)d_out;
    float* out_dmap = out_logp + (size_t)N_RES * KNEI * NBINS;

    proj_kernel<<<1024, 256, 0, stream>>>(features, W_left, W_right,
                                          resi, chain, batch, W_pos,
                                          leftbf, rightbf, meta, wposbf);
    prepass_kernel<<<NPAIRS / 256, 256, 0, stream>>>(nbr, meta, rs);
    pair_kernel<<<2048, 256, 0, stream>>>(leftbf, rightbf, rs, nbr, wposbf,
                                          ln_scale, ln_bias, W1, b1, W2, b2,
                                          out_logp, out_dmap);
}